// Round 10
// baseline (5800.825 us; speedup 1.0000x reference)
//
#include <hip/hip_runtime.h>

// Problem constants (from setup_inputs: B=16, N=16384, D=128, S=N/4)
#define BATCH    16
#define NPTS     16384
#define NSAMP    4096
#define NTHREADS 1024
#define PPT      16
#define NWAVE    16

// DPP move helper (disabled lanes keep old value = own value)
template<int CTRL, int RM>
__device__ __forceinline__ float dpp_movf(float v) {
    return __int_as_float(__builtin_amdgcn_update_dpp(
        __float_as_int(v), __float_as_int(v), CTRL, RM, 0xF, false));
}

__device__ __forceinline__ float wave_max64(float v) {
    v = fmaxf(v, dpp_movf<0x111, 0xF>(v));   // row_shr:1
    v = fmaxf(v, dpp_movf<0x112, 0xF>(v));   // row_shr:2
    v = fmaxf(v, dpp_movf<0x114, 0xF>(v));   // row_shr:4
    v = fmaxf(v, dpp_movf<0x118, 0xF>(v));   // row_shr:8
    v = fmaxf(v, dpp_movf<0x142, 0xA>(v));   // row_bcast:15
    v = fmaxf(v, dpp_movf<0x143, 0xC>(v));   // row_bcast:31 -> lane 63 = max
    return v;
}
__device__ __forceinline__ float wave_min64(float v) {
    v = fminf(v, dpp_movf<0x111, 0xF>(v));
    v = fminf(v, dpp_movf<0x112, 0xF>(v));
    v = fminf(v, dpp_movf<0x114, 0xF>(v));
    v = fminf(v, dpp_movf<0x118, 0xF>(v));
    v = fminf(v, dpp_movf<0x142, 0xA>(v));
    v = fminf(v, dpp_movf<0x143, 0xC>(v));
    return v;
}
__device__ __forceinline__ float bcast63(float v) {
    return __int_as_float(__builtin_amdgcn_readlane(__float_as_int(v), 63));
}

// order-preserving float -> uint map (IEEE total order)
__device__ __forceinline__ unsigned xform(float f) {
    unsigned u = __float_as_uint(f);
    return (u & 0x80000000u) ? ~u : (u | 0x80000000u);
}

// (segmented) bitonic sort of s_key in LDS; segbound = segment size (pow2).
__device__ __forceinline__ void bitonic_lds(unsigned* s_key, int tid, int segbound) {
    for (int k = 2; k <= segbound; k <<= 1) {
        for (int j = k >> 1; j > 0; j >>= 1) {
            __syncthreads();
            #pragma unroll
            for (int m = 0; m < PPT; ++m) {
                int i = (m << 10) | tid;
                int l = i ^ j;
                if (l > i) {
                    unsigned a = s_key[i], c2 = s_key[l];
                    bool up = ((i & k) == 0);
                    if ((a > c2) == up) { s_key[i] = c2; s_key[l] = a; }
                }
            }
        }
    }
}

// -----------------------------------------------------------------------------
// FPS, rank-split grid (8x8x16 cells of 16 pts) + per-cell exact pruning +
// CUBE-CLUSTERED WAVES: wave w owns a 4x4x4 block of cells (region shape
// 1/2 x 1/2 x 1/4) instead of a z-spanning half-slab -- the active ball
// around each new centroid now trips ~2x fewer waves (round-9 counters:
// 7.3/16 waves recomputing). Plus a wave-level bbox pre-test (sound: wave
// box contains cell boxes; mval = exact cached wave max).
// Exact reference semantics: dist=min(dist,(dx2+dy2)+dz2) fp32 no-FMA,
// argmax first-original-index (all tie paths compare original indices).
// -----------------------------------------------------------------------------
__global__ __launch_bounds__(NTHREADS, 4) void fps_kernel(
    const float* __restrict__ xyz, int* __restrict__ sorted_idx)
{
    __shared__ unsigned s_key[NPTS];                 // 64 KiB
    __shared__ unsigned s_bitmap[NPTS / 32];         // 2 KiB
    __shared__ unsigned long long s_slot[2][NWAVE];  // parity {max_bits, orig}
    __shared__ float s_ccf[2][NWAVE * 3];            // parity candidate coords
    __shared__ int s_wt[NWAVE];                      // tail scan totals

    const int tid  = threadIdx.x;
    const int lane = tid & 63;
    const int wid  = tid >> 6;
    const int b    = blockIdx.x;

    if (tid < NPTS / 32) s_bitmap[tid] = 0u;

    const float* xb = xyz + (size_t)b * NPTS * 3;

    // ---- partition sort 1: by x (full 16384) ----
    #pragma unroll
    for (int k = 0; k < PPT; ++k) {
        int i = (tid << 4) + k;
        s_key[i] = (xform(xb[3 * i]) & 0xFFFFC000u) | (unsigned)i;
    }
    bitonic_lds(s_key, tid, NPTS);
    __syncthreads();

    // ---- sort 2: by y within 8 x-slabs of 2048 ----
    #pragma unroll
    for (int m = 0; m < PPT; ++m) {
        int p = (m << 10) | tid;
        unsigned orig = s_key[p] & 0x3FFFu;
        s_key[p] = (xform(xb[3 * orig + 1]) & 0xFFFFC000u) | orig;
    }
    bitonic_lds(s_key, tid, 2048);
    __syncthreads();

    // ---- sort 3: by z within 64 columns of 256 ----
    #pragma unroll
    for (int m = 0; m < PPT; ++m) {
        int p = (m << 10) | tid;
        unsigned orig = s_key[p] & 0x3FFFu;
        s_key[p] = (xform(xb[3 * orig + 2]) & 0xFFFFC000u) | orig;
    }
    bitonic_lds(s_key, tid, 256);
    __syncthreads();

    // ---- CUBE REMAP: thread (wid,lane) owns cell (sx,sy,sz) so that each
    // wave covers a 4x4x4 block of the 8x8x16 cell grid ----
    int sx = ((wid >> 3) << 2) | (lane >> 4);           // 0..7
    int sy = (((wid >> 2) & 1) << 2) | ((lane >> 2) & 3); // 0..7
    int sz = ((wid & 3) << 2) | (lane & 3);             // 0..15
    int rsrc = (sx << 7) | (sy << 4) | sz;              // source cell id (rank order)

    unsigned o[PPT];
    #pragma unroll
    for (int k = 0; k < PPT; ++k) o[k] = s_key[(rsrc << 4) + k] & 0x3FFFu;
    __syncthreads();   // all cross-thread reads of s_key done before overwrite

    // in-register sort of the 16 origs ascending (odd-even network)
    #pragma unroll
    for (int r = 0; r < 16; ++r) {
        #pragma unroll
        for (int i = (r & 1); i + 1 < PPT; i += 2) {
            unsigned lo = min(o[i], o[i + 1]);
            unsigned hi = max(o[i], o[i + 1]);
            o[i] = lo; o[i + 1] = hi;
        }
    }
    #pragma unroll
    for (int k = 0; k < PPT; ++k) s_key[(tid << 4) + k] = o[k];

    // ---- gather coords; tight cell bbox; init pd/tmax ----
    float px[PPT], py[PPT], pz[PPT], pd[PPT];
    float bxl = 1e30f, byl = 1e30f, bzl = 1e30f;
    float bxh = -1e30f, byh = -1e30f, bzh = -1e30f;
    #pragma unroll
    for (int k = 0; k < PPT; ++k) {
        int g = (int)o[k];
        px[k] = xb[3 * g]; py[k] = xb[3 * g + 1]; pz[k] = xb[3 * g + 2];
        pd[k] = 1e10f;
        bxl = fminf(bxl, px[k]); bxh = fmaxf(bxh, px[k]);
        byl = fminf(byl, py[k]); byh = fmaxf(byh, py[k]);
        bzl = fminf(bzl, pz[k]); bzh = fmaxf(bzh, pz[k]);
    }
    float tmax = 1e10f;

    // ---- wave bbox (union of its 64 cell boxes), broadcast uniform ----
    float wbxl = bcast63(wave_min64(bxl)), wbxh = bcast63(wave_max64(bxh));
    float wbyl = bcast63(wave_min64(byl)), wbyh = bcast63(wave_max64(byh));
    float wbzl = bcast63(wave_min64(bzl)), wbzh = bcast63(wave_max64(bzh));

    // cached per-wave candidate (uniform); published while dirty
    float mval = 1e10f, mcx = 0.f, mcy = 0.f, mcz = 0.f;
    int   morig = 0, dirty = 0;

    float cx = xb[0], cy = xb[1], cz = xb[2];   // initial farthest = index 0
    if (tid == 0) s_bitmap[0] = 1u;
    __syncthreads();

    for (int s = 0; s < NSAMP - 1; ++s) {
        const int p = s & 1;

        // ---- wave-level pre-test (mval = exact cached wave max) ----
        float wtx = fmaxf(fmaxf(__fsub_rn(wbxl, cx), __fsub_rn(cx, wbxh)), 0.f);
        float wty = fmaxf(fmaxf(__fsub_rn(wbyl, cy), __fsub_rn(cy, wbyh)), 0.f);
        float wtz = fmaxf(fmaxf(__fsub_rn(wbzl, cz), __fsub_rn(cz, wbzh)), 0.f);
        float wmd2 = 0.9999f * __fadd_rn(__fadd_rn(__fmul_rn(wtx, wtx),
                                                   __fmul_rn(wty, wty)),
                                         __fmul_rn(wtz, wtz));
        if (wmd2 < mval) {
            // ---- per-cell exact skip test ----
            float tx = fmaxf(fmaxf(__fsub_rn(bxl, cx), __fsub_rn(cx, bxh)), 0.f);
            float ty = fmaxf(fmaxf(__fsub_rn(byl, cy), __fsub_rn(cy, byh)), 0.f);
            float tz = fmaxf(fmaxf(__fsub_rn(bzl, cz), __fsub_rn(cz, bzh)), 0.f);
            float md2 = 0.9999f * __fadd_rn(__fadd_rn(__fmul_rn(tx, tx),
                                                      __fmul_rn(ty, ty)),
                                            __fmul_rn(tz, tz));
            if (__ballot(md2 < tmax) != 0ull) {   // recompute whole wave
                float bv = -1.0f;
                int   bk = 0;
                #pragma unroll
                for (int k = 0; k < PPT; ++k) {
                    float dx = __fsub_rn(px[k], cx);
                    float dy = __fsub_rn(py[k], cy);
                    float dz = __fsub_rn(pz[k], cz);
                    float d  = __fadd_rn(__fadd_rn(__fmul_rn(dx, dx),
                                                   __fmul_rn(dy, dy)),
                                         __fmul_rn(dz, dz));
                    float nd = fminf(pd[k], d);
                    pd[k] = nd;
                    if (nd > bv) { bv = nd; bk = k; }  // strict >: min orig (k sorted)
                }
                tmax = bv;
                int bo_mine = (int)s_key[(tid << 4) + bk];

                float wv = wave_max64(bv);
                int   mb = __builtin_amdgcn_readlane(__float_as_int(wv), 63);
                float mw = __int_as_float(mb);
                unsigned long long mk = __ballot(bv == mw);
                int sl, bo;
                if (__popcll(mk) == 1) {                   // unique max lane
                    sl = __ffsll(mk) - 1;
                    bo = __builtin_amdgcn_readlane(bo_mine, sl);
                } else {                                   // rare: min orig over ties
                    unsigned long long t = mk;
                    bo = 0x7FFFFFFF; sl = 0;
                    while (t) {
                        int l = __ffsll(t) - 1; t &= t - 1;
                        int b2 = __builtin_amdgcn_readlane(bo_mine, l);
                        if (b2 < bo) { bo = b2; sl = l; }
                    }
                }
                float ax = px[0], ay = py[0], az = pz[0];
                #pragma unroll
                for (int k = 1; k < PPT; ++k)
                    if (bk == k) { ax = px[k]; ay = py[k]; az = pz[k]; }
                mcx = __int_as_float(__builtin_amdgcn_readlane(__float_as_int(ax), sl));
                mcy = __int_as_float(__builtin_amdgcn_readlane(__float_as_int(ay), sl));
                mcz = __int_as_float(__builtin_amdgcn_readlane(__float_as_int(az), sl));
                mval = mw; morig = bo; dirty = 2;
            }
        }

        if (dirty > 0) {                   // publish cached candidate (both parities)
            if (lane == 0) {
                s_slot[p][wid] =
                    ((unsigned long long)(unsigned)__float_as_int(mval) << 32) |
                    (unsigned)morig;
                s_ccf[p][wid * 3 + 0] = mcx;
                s_ccf[p][wid * 3 + 1] = mcy;
                s_ccf[p][wid * 3 + 2] = mcz;
            }
            dirty -= 1;
        }

        __syncthreads();   // the ONLY barrier per iteration

        // ---- block winner over 16 wave slots; coords read in parallel ----
        unsigned long long key = s_slot[p][lane & 15];
        float cf = s_ccf[p][lane < 48 ? lane : 0];
        float cv = __int_as_float((int)(key >> 32));
        int   ci = (int)(unsigned)key;
        float rv = cv;
        rv = fmaxf(rv, dpp_movf<0x111, 0xF>(rv));
        rv = fmaxf(rv, dpp_movf<0x112, 0xF>(rv));
        rv = fmaxf(rv, dpp_movf<0x114, 0xF>(rv));
        rv = fmaxf(rv, dpp_movf<0x118, 0xF>(rv));  // lane 15 of row = max
        int   gmb = __builtin_amdgcn_readlane(__float_as_int(rv), 15);
        float gm  = __int_as_float(gmb);
        unsigned long long m2 = __ballot(cv == gm);
        int w, g;
        if (__popcll(m2) == 4) {                   // unique winning wave
            w = __ffsll(m2) - 1;
            g = __builtin_amdgcn_readlane(ci, w);
        } else {                                   // rare: min orig across waves
            unsigned long long t = m2 & 0xFFFFull;
            g = 0x7FFFFFFF; w = 0;
            while (t) {
                int l = __ffsll(t) - 1; t &= t - 1;
                int g2 = __builtin_amdgcn_readlane(ci, l);
                if (g2 < g) { g = g2; w = l; }
            }
        }
        cx = __int_as_float(__builtin_amdgcn_readlane(__float_as_int(cf), w * 3 + 0));
        cy = __int_as_float(__builtin_amdgcn_readlane(__float_as_int(cf), w * 3 + 1));
        cz = __int_as_float(__builtin_amdgcn_readlane(__float_as_int(cf), w * 3 + 2));

        if (tid == 0) s_bitmap[g >> 5] |= (1u << (g & 31));
    }
    __syncthreads();

    // ---- tail: bitmap -> ascending index list via block prefix scan ----
    const int nwords = NPTS / 32;   // 512
    unsigned word = (tid < nwords) ? s_bitmap[tid] : 0u;
    int cnt = __popc(word);
    int inc = cnt;
    #pragma unroll
    for (int off = 1; off < 64; off <<= 1) {
        int n = __shfl_up(inc, off);
        if (lane >= off) inc += n;
    }
    if (lane == 63) s_wt[wid] = inc;
    __syncthreads();
    int base = inc - cnt;
    for (int w = 0; w < wid; ++w) base += s_wt[w];
    int* sb = sorted_idx + (size_t)b * NSAMP;
    int pos = base;
    unsigned wmask = word;
    while (wmask) {
        int k = __ffs(wmask) - 1;
        wmask &= wmask - 1;
        sb[pos++] = tid * 32 + k;
    }
}

// -----------------------------------------------------------------------------
// Gather kernel: one wave per sampled row.
//   out0 = new_xyz [B,S,3]; out1 = concat(xyz, points) [B,S,1,131]; out2 [B,S,128]
// -----------------------------------------------------------------------------
__global__ void gather_kernel(
    const float* __restrict__ xyz, const float* __restrict__ points,
    const float* __restrict__ pres, const int* __restrict__ sorted_idx,
    float* __restrict__ out0, float* __restrict__ out1, float* __restrict__ out2)
{
    int gw   = (int)((blockIdx.x * (unsigned)blockDim.x + threadIdx.x) >> 6);
    int lane = threadIdx.x & 63;
    if (gw >= BATCH * NSAMP) return;
    int b = gw >> 12;               // NSAMP == 4096
    int i = sorted_idx[gw];

    const float* xs = xyz    + ((size_t)b * NPTS + i) * 3;
    const float* ps = points + ((size_t)b * NPTS + i) * 128;
    const float* rs = pres   + ((size_t)b * NPTS + i) * 128;

    if (lane < 3) out0[(size_t)gw * 3 + lane] = xs[lane];

    float* o1 = out1 + (size_t)gw * 131;
    #pragma unroll
    for (int j = 0; j < 3; ++j) {
        int c = lane + 64 * j;
        if (c < 131) o1[c] = (c < 3) ? xs[c] : ps[c - 3];
    }

    const float2* r2 = (const float2*)rs;
    float2* o2 = (float2*)(out2 + (size_t)gw * 128);
    o2[lane] = r2[lane];
}

extern "C" void kernel_launch(void* const* d_in, const int* in_sizes, int n_in,
                              void* d_out, int out_size, void* d_ws, size_t ws_size,
                              hipStream_t stream)
{
    const float* xyz    = (const float*)d_in[0];
    const float* points = (const float*)d_in[1];
    const float* pres   = (const float*)d_in[2];

    float* out  = (float*)d_out;
    float* out0 = out;                                     // B*S*3
    float* out1 = out0 + (size_t)BATCH * NSAMP * 3;        // B*S*131
    float* out2 = out1 + (size_t)BATCH * NSAMP * 131;      // B*S*128

    int* sorted = (int*)d_ws;   // B*S ints = 256 KiB scratch

    fps_kernel<<<BATCH, NTHREADS, 0, stream>>>(xyz, sorted);

    int total_threads = BATCH * NSAMP * 64;   // one wave per sampled row
    int threads = 256;
    int blocks  = total_threads / threads;
    gather_kernel<<<blocks, threads, 0, stream>>>(xyz, points, pres, sorted,
                                                  out0, out1, out2);
}